// Round 14
// baseline (292.708 us; speedup 1.0000x reference)
//
#include <hip/hip_runtime.h>
#include <math.h>

#define B_ROWS 32768
#define K_CODES 4096
#define D_DIM 128
#define MARGIN 1.5e-3f
#define CAP 64

typedef short bf16x8 __attribute__((ext_vector_type(8)));
typedef float f32x4 __attribute__((ext_vector_type(4)));

// RNE float->bf16 (finite inputs only)
__device__ __forceinline__ unsigned short f2bf(float f) {
  union { float f; unsigned int u; } v; v.f = f;
  unsigned int r = (v.u + 0x7FFFu + ((v.u >> 16) & 1u)) >> 16;
  return (unsigned short)r;
}

// ---------------------------------------------------------------------------
// Kernel 1: prep — x2/e2 (numpy pairwise order, validated) + eb bf16 cast in
// MFMA-FRAGMENT order (validated r4): og = tile*256 + ks*64 + q*16 + lr maps
// to emb row tile*16+lr, cols ks*32+q*8 .. +7.
// ---------------------------------------------------------------------------
__global__ __launch_bounds__(256) void prep(const float* __restrict__ x,
                                            const float* __restrict__ emb,
                                            float* __restrict__ x2,
                                            float* __restrict__ e2,
                                            unsigned short* __restrict__ ebb) {
  const int t0 = blockIdx.x * 256 + threadIdx.x;
  const int stride = gridDim.x * 256;
  for (int s = t0; s < B_ROWS * 8; s += stride) {
    int row = s >> 3, lane = s & 7;
    const float* src = x + (size_t)row * D_DIM;
    float v = src[lane];
    float t = v * v;
    asm volatile("" : "+v"(t));
    float acc = t;
#pragma unroll
    for (int i = 1; i < 16; ++i) {
      float w = src[i * 8 + lane];
      float tt = w * w;
      asm volatile("" : "+v"(tt));
      acc = acc + tt;
    }
    acc = acc + __shfl_xor(acc, 1, 64);
    acc = acc + __shfl_xor(acc, 2, 64);
    acc = acc + __shfl_xor(acc, 4, 64);
    if (lane == 0) x2[row] = acc;
  }
  for (int s = t0; s < K_CODES * 8; s += stride) {
    int row = s >> 3, lane = s & 7;
    const float* src = emb + (size_t)row * D_DIM;
    float v = src[lane];
    float t = v * v;
    asm volatile("" : "+v"(t));
    float acc = t;
#pragma unroll
    for (int i = 1; i < 16; ++i) {
      float w = src[i * 8 + lane];
      float tt = w * w;
      asm volatile("" : "+v"(tt));
      acc = acc + tt;
    }
    acc = acc + __shfl_xor(acc, 1, 64);
    acc = acc + __shfl_xor(acc, 2, 64);
    acc = acc + __shfl_xor(acc, 4, 64);
    if (lane == 0) e2[row] = acc;
  }
  for (int og = t0; og < K_CODES * D_DIM / 8; og += stride) {
    int tile = og >> 8, ks = (og >> 6) & 3, qq = (og >> 4) & 3, lr2 = og & 15;
    const float* src = emb + (size_t)(tile * 16 + lr2) * D_DIM + ks * 32 + qq * 8;
    float4 a = *(const float4*)src;
    float4 b = *(const float4*)(src + 4);
    ushort4 o0 = make_ushort4(f2bf(a.x), f2bf(a.y), f2bf(a.z), f2bf(a.w));
    ushort4 o1 = make_ushort4(f2bf(b.x), f2bf(b.y), f2bf(b.z), f2bf(b.w));
    ((ushort4*)ebb)[og * 2] = o0;
    ((ushort4*)ebb)[og * 2 + 1] = o1;
  }
}

// ---------------------------------------------------------------------------
// Kernel 2a1: vq_scanA — K-SPLIT pass A.  1024 blocks: (row-group, half).
// Each block: 64 rows x 2048 codes with the r12-validated 256-thread loop
// body (VGPR ~84, no spills).  Same total eb traffic as r12's pass A
// (each row-group still streams all 4096 codes once), but 2x the blocks ->
// 4 blocks/CU = 4 waves/SIMD latency hiding.  Writes per-(row,half) partial
// min (exact min, order-independent).
// ---------------------------------------------------------------------------
__global__ __launch_bounds__(256, 2) void vq_scanA(
    const float* __restrict__ x, const unsigned short* __restrict__ eb,
    const float* __restrict__ e2g, float* __restrict__ pmin) {
  __shared__ float m2[256];
  const int tid = threadIdx.x;
  const int wid = tid >> 6;
  const int lane = tid & 63;
  const int q = lane >> 4, lr = lane & 15;
  const int rg = blockIdx.x >> 1, h = blockIdx.x & 1;
  const int rowbase = rg * 64;
  const bf16x8* ebv = (const bf16x8*)eb;

  // hoist A fragments (r12 verbatim)
  bf16x8 af[4][4];
#pragma unroll
  for (int mi = 0; mi < 4; ++mi) {
    const float* xr = x + (size_t)(rowbase + mi * 16 + lr) * D_DIM;
#pragma unroll
    for (int ks = 0; ks < 4; ++ks) {
      float4 v0 = *(const float4*)(xr + ks * 32 + q * 8);
      float4 v1 = *(const float4*)(xr + ks * 32 + q * 8 + 4);
      bf16x8 f;
      f[0] = (short)f2bf(v0.x); f[1] = (short)f2bf(v0.y);
      f[2] = (short)f2bf(v0.z); f[3] = (short)f2bf(v0.w);
      f[4] = (short)f2bf(v1.x); f[5] = (short)f2bf(v1.y);
      f[6] = (short)f2bf(v1.z); f[7] = (short)f2bf(v1.w);
      af[mi][ks] = f;
    }
  }

  float rm[4][4];
#pragma unroll
  for (int mi = 0; mi < 4; ++mi)
#pragma unroll
    for (int rgi = 0; rgi < 4; ++rgi) rm[mi][rgi] = 3.4e38f;

#pragma unroll 2
  for (int ch0 = 0; ch0 < 16; ++ch0) {
    int ch = h * 16 + ch0;
    bf16x8 bf[2][4];
#pragma unroll
    for (int ni = 0; ni < 2; ++ni) {
      const bf16x8* tb = ebv + ((size_t)(ch * 8 + wid * 2 + ni) * 256 + lane);
#pragma unroll
      for (int ks = 0; ks < 4; ++ks) bf[ni][ks] = tb[ks * 64];
    }
    f32x4 acc[4][2];
#pragma unroll
    for (int mi = 0; mi < 4; ++mi)
#pragma unroll
      for (int ni = 0; ni < 2; ++ni) {
        f32x4 z = {0.f, 0.f, 0.f, 0.f};
        acc[mi][ni] = z;
      }
#pragma unroll
    for (int ks = 0; ks < 4; ++ks)
#pragma unroll
      for (int mi = 0; mi < 4; ++mi)
#pragma unroll
        for (int ni = 0; ni < 2; ++ni)
          acc[mi][ni] = __builtin_amdgcn_mfma_f32_16x16x32_bf16(
              af[mi][ks], bf[ni][ks], acc[mi][ni], 0, 0, 0);
#pragma unroll
    for (int ni = 0; ni < 2; ++ni) {
      float ev = e2g[ch * 128 + (wid * 2 + ni) * 16 + lr];
#pragma unroll
      for (int mi = 0; mi < 4; ++mi)
#pragma unroll
        for (int rgi = 0; rgi < 4; ++rgi) {
          float t = __builtin_fmaf(-2.0f, acc[mi][ni][rgi], ev);
          rm[mi][rgi] = fminf(rm[mi][rgi], t);
        }
    }
  }

  // reduce min across the 16 col-lanes, then across the 4 waves
#pragma unroll
  for (int mi = 0; mi < 4; ++mi)
#pragma unroll
    for (int rgi = 0; rgi < 4; ++rgi) {
      float v = rm[mi][rgi];
      v = fminf(v, __shfl_xor(v, 1, 64));
      v = fminf(v, __shfl_xor(v, 2, 64));
      v = fminf(v, __shfl_xor(v, 4, 64));
      v = fminf(v, __shfl_xor(v, 8, 64));
      if (lr == 0) m2[(mi * 16 + q * 4 + rgi) * 4 + wid] = v;
    }
  __syncthreads();
  if (tid < 64) {
    float a = fminf(m2[tid * 4], m2[tid * 4 + 1]);
    float b = fminf(m2[tid * 4 + 2], m2[tid * 4 + 3]);
    pmin[(size_t)(rowbase + tid) * 2 + h] = fminf(a, b);
  }
}

// ---------------------------------------------------------------------------
// Kernel 2a2: vq_merge — mlims[row] = min(halves) + MARGIN.  Exact min is
// order-independent -> bit-identical to r12's single-kernel mlims.
// ---------------------------------------------------------------------------
__global__ __launch_bounds__(256) void vq_merge(const float* __restrict__ pmin,
                                               float* __restrict__ mlims) {
  const int r = blockIdx.x * 256 + threadIdx.x;
  mlims[r] = fminf(pmin[(size_t)r * 2], pmin[(size_t)r * 2 + 1]) + MARGIN;
}

// ---------------------------------------------------------------------------
// Kernel 2a3: vq_scanB — K-SPLIT pass B.  1024 blocks, same loop body as
// r12's pass B over this block's half of the codebook.  Slots in the shared
// per-row list (capacity CAP=64, same as r12) are allocated by device-scope
// atomicAdd on cnt_g[row] (~300K adds over 32768 addresses; r11 measured
// this class of atomics at ~10us for 33K).  Candidate SET and overflow
// semantics identical to r12; list order irrelevant (lexicographic rescore).
// ---------------------------------------------------------------------------
__global__ __launch_bounds__(256, 2) void vq_scanB(
    const float* __restrict__ x, const unsigned short* __restrict__ eb,
    const float* __restrict__ e2g, const float* __restrict__ mlims,
    unsigned short* __restrict__ lists_g, unsigned int* __restrict__ cnt_g) {
  const int tid = threadIdx.x;
  const int wid = tid >> 6;
  const int lane = tid & 63;
  const int q = lane >> 4, lr = lane & 15;
  const int rg = blockIdx.x >> 1, h = blockIdx.x & 1;
  const int rowbase = rg * 64;
  const bf16x8* ebv = (const bf16x8*)eb;

  // hoist A fragments (r12 verbatim)
  bf16x8 af[4][4];
#pragma unroll
  for (int mi = 0; mi < 4; ++mi) {
    const float* xr = x + (size_t)(rowbase + mi * 16 + lr) * D_DIM;
#pragma unroll
    for (int ks = 0; ks < 4; ++ks) {
      float4 v0 = *(const float4*)(xr + ks * 32 + q * 8);
      float4 v1 = *(const float4*)(xr + ks * 32 + q * 8 + 4);
      bf16x8 f;
      f[0] = (short)f2bf(v0.x); f[1] = (short)f2bf(v0.y);
      f[2] = (short)f2bf(v0.z); f[3] = (short)f2bf(v0.w);
      f[4] = (short)f2bf(v1.x); f[5] = (short)f2bf(v1.y);
      f[6] = (short)f2bf(v1.z); f[7] = (short)f2bf(v1.w);
      af[mi][ks] = f;
    }
  }

  float ml[4][4];
#pragma unroll
  for (int mi = 0; mi < 4; ++mi)
#pragma unroll
    for (int rgi = 0; rgi < 4; ++rgi)
      ml[mi][rgi] = mlims[rowbase + mi * 16 + q * 4 + rgi];

#pragma unroll 2
  for (int ch0 = 0; ch0 < 16; ++ch0) {
    int ch = h * 16 + ch0;
    bf16x8 bf[2][4];
#pragma unroll
    for (int ni = 0; ni < 2; ++ni) {
      const bf16x8* tb = ebv + ((size_t)(ch * 8 + wid * 2 + ni) * 256 + lane);
#pragma unroll
      for (int ks = 0; ks < 4; ++ks) bf[ni][ks] = tb[ks * 64];
    }
    f32x4 acc[4][2];
#pragma unroll
    for (int mi = 0; mi < 4; ++mi)
#pragma unroll
      for (int ni = 0; ni < 2; ++ni) {
        f32x4 z = {0.f, 0.f, 0.f, 0.f};
        acc[mi][ni] = z;
      }
#pragma unroll
    for (int ks = 0; ks < 4; ++ks)
#pragma unroll
      for (int mi = 0; mi < 4; ++mi)
#pragma unroll
        for (int ni = 0; ni < 2; ++ni)
          acc[mi][ni] = __builtin_amdgcn_mfma_f32_16x16x32_bf16(
              af[mi][ks], bf[ni][ks], acc[mi][ni], 0, 0, 0);
#pragma unroll
    for (int ni = 0; ni < 2; ++ni) {
      int colbase = ch * 128 + (wid * 2 + ni) * 16 + lr;
      float ev = e2g[colbase];
#pragma unroll
      for (int mi = 0; mi < 4; ++mi)
#pragma unroll
        for (int rgi = 0; rgi < 4; ++rgi) {
          float t = __builtin_fmaf(-2.0f, acc[mi][ni][rgi], ev);
          if (t <= ml[mi][rgi]) {
            int growc = rowbase + mi * 16 + q * 4 + rgi;
            unsigned int p = atomicAdd(&cnt_g[growc], 1u);
            if (p < CAP) lists_g[(size_t)growc * CAP + p] = (unsigned short)colbase;
          }
        }
    }
  }
}

// ---------------------------------------------------------------------------
// Kernel 2b: vq_tail2 — rescore + gather/losses (r12 verbatim: no global
// atomics, CAP=64, parallel fallback reduction).  32 rows/block.
// ---------------------------------------------------------------------------
__global__ __launch_bounds__(256) void vq_tail2(
    const float* __restrict__ x, const float* __restrict__ emb,
    const float* __restrict__ x2g, const float* __restrict__ e2g,
    const unsigned short* __restrict__ lists_g,
    const unsigned int* __restrict__ cnt_g,
    float* __restrict__ out_q, float* __restrict__ out_idx,
    unsigned int* __restrict__ bidx_g, double* __restrict__ bpart) {
  __shared__ float xf[32 * 132];       // 16896B
  __shared__ float redv[256];
  __shared__ int redi[256];
  __shared__ unsigned int cnts[32];
  __shared__ int bidxs[32];
  __shared__ double lred[8];
  __shared__ int ovflag;

  const int tid = threadIdx.x;
  const int wid = tid >> 6;
  const int lane = tid & 63;
  const int rowbase = blockIdx.x * 32;

  if (tid < 32) cnts[tid] = cnt_g[rowbase + tid];
  // stage fp32 x rows (coalesced)
  {
    const float4* src = (const float4*)(x + (size_t)rowbase * D_DIM);
#pragma unroll
    for (int p = 0; p < 4; ++p) {
      int idx = p * 256 + tid;            // float4 index over 32x128
      int r = idx >> 5, c = idx & 31;
      *(float4*)(xf + r * 132 + c * 4) = src[idx];
    }
  }
  __syncthreads();

  // 8 lanes per row; per-candidate fp32 chain identical to validated version.
  {
    int gr = tid >> 3, sub = tid & 7;
    int c = (int)cnts[gr];
    if (c <= CAP) {
      float xs2 = x2g[rowbase + gr];
      const float* xr = xf + gr * 132;
      float best = 3.4e38f;
      int bidx = 0x7fffffff;
      const unsigned short* lrow = lists_g + (size_t)(rowbase + gr) * CAP;
      for (int j = sub; j < c; j += 8) {
        int col = lrow[j];
        float dot = 0.f;
        const float4* ev = (const float4*)(emb + (size_t)col * D_DIM);
#pragma unroll 8
        for (int d4 = 0; d4 < 32; ++d4) {  // exact ascending-d fmaf chain
          float4 e4 = ev[d4];
          dot = __builtin_fmaf(xr[d4 * 4 + 0], e4.x, dot);
          dot = __builtin_fmaf(xr[d4 * 4 + 1], e4.y, dot);
          dot = __builtin_fmaf(xr[d4 * 4 + 2], e4.z, dot);
          dot = __builtin_fmaf(xr[d4 * 4 + 3], e4.w, dot);
        }
        float t1 = xs2 + e2g[col];                 // fl(x2+e2)
        float s = __builtin_fmaf(-2.0f, dot, t1);  // fl(t1 - 2*dot)
        if (s < best || (s == best && col < bidx)) { best = s; bidx = col; }
      }
#pragma unroll
      for (int off = 1; off <= 4; off <<= 1) {
        float ov = __shfl_xor(best, off, 64);
        int oi = __shfl_xor(bidx, off, 64);
        if (ov < best || (ov == best && oi < bidx)) { best = ov; bidx = oi; }
      }
      if (sub == 0) {
        out_idx[rowbase + gr] = (float)bidx;
        bidxs[gr] = bidx;
        bidx_g[rowbase + gr] = (unsigned int)bidx;
      }
    }
  }

  // overflow flag (block-uniform; with CAP=64 expected never taken)
  if (tid == 0) {
    int f = 0;
    for (int r = 0; r < 32; ++r) f |= (cnts[r] > CAP) ? 1 : 0;
    ovflag = f;
  }
  __syncthreads();

  if (ovflag) {
    for (int r = 0; r < 32; ++r) {
      if (cnts[r] <= CAP) continue;
      float xs2 = x2g[rowbase + r];
      const float* xr = xf + r * 132;
      float lbest = 3.4e38f;
      int lidx = 0x7fffffff;
      for (int c0 = tid; c0 < K_CODES; c0 += 256) {
        float dot = 0.f;
        const float4* ev = (const float4*)(emb + (size_t)c0 * D_DIM);
        for (int d4 = 0; d4 < 32; ++d4) {
          float4 e4 = ev[d4];
          dot = __builtin_fmaf(xr[d4 * 4 + 0], e4.x, dot);
          dot = __builtin_fmaf(xr[d4 * 4 + 1], e4.y, dot);
          dot = __builtin_fmaf(xr[d4 * 4 + 2], e4.z, dot);
          dot = __builtin_fmaf(xr[d4 * 4 + 3], e4.w, dot);
        }
        float s = __builtin_fmaf(-2.0f, dot, xs2 + e2g[c0]);
        if (s < lbest || (s == lbest && c0 < lidx)) { lbest = s; lidx = c0; }
      }
      redv[tid] = lbest;
      redi[tid] = lidx;
      __syncthreads();
      // parallel lexicographic reduce: 256 -> 128 -> 64 -> wave shuffle
      if (tid < 128) {
        float v2 = redv[tid + 128]; int i2 = redi[tid + 128];
        if (v2 < redv[tid] || (v2 == redv[tid] && i2 < redi[tid])) {
          redv[tid] = v2; redi[tid] = i2;
        }
      }
      __syncthreads();
      if (tid < 64) {
        float bv = redv[tid]; int bi = redi[tid];
        float v2 = redv[tid + 64]; int i2 = redi[tid + 64];
        if (v2 < bv || (v2 == bv && i2 < bi)) { bv = v2; bi = i2; }
#pragma unroll
        for (int off = 32; off >= 1; off >>= 1) {
          float ov = __shfl_down(bv, off, 64);
          int oi = __shfl_down(bi, off, 64);
          if (ov < bv || (ov == bv && oi < bi)) { bv = ov; bi = oi; }
        }
        if (tid == 0) {
          out_idx[rowbase + r] = (float)bi;
          bidxs[r] = bi;
          bidx_g[rowbase + r] = (unsigned int)bi;
        }
      }
      __syncthreads();
    }
  }
  __syncthreads();  // bidxs ready for all rows

  // ---------------- fused gather + straight-through + losses ----------------
  {
    int gr = tid >> 3, seg = tid & 7;   // 8 threads/row, 16 floats each
    int gidx = bidxs[gr];
    const float4* ev = (const float4*)(emb + (size_t)gidx * D_DIM + seg * 16);
    const float* xvp = xf + gr * 132 + seg * 16;
    float4* oq = (float4*)(out_q + (size_t)(rowbase + gr) * D_DIM + seg * 16);
    double es = 0.0, qs = 0.0;
#pragma unroll
    for (int j = 0; j < 4; ++j) {
      float4 e4 = ev[j];
      float4 xv = *(const float4*)(xvp + j * 4);
      float d0 = e4.x - xv.x, d1 = e4.y - xv.y, d2 = e4.z - xv.z, d3 = e4.w - xv.w;
      float s0 = xv.x + d0, s1 = xv.y + d1, s2 = xv.z + d2, s3 = xv.w + d3;
      oq[j] = make_float4(s0, s1, s2, s3);
      float g0 = s0 - xv.x, g1 = s1 - xv.y, g2 = s2 - xv.z, g3 = s3 - xv.w;
      es += (double)(d0 * d0) + (double)(d1 * d1) + (double)(d2 * d2) + (double)(d3 * d3);
      qs += (double)(g0 * g0) + (double)(g1 * g1) + (double)(g2 * g2) + (double)(g3 * g3);
    }
#pragma unroll
    for (int off = 32; off >= 1; off >>= 1) {
      es += __shfl_down(es, off, 64);
      qs += __shfl_down(qs, off, 64);
    }
    if (lane == 0) { lred[wid * 2] = es; lred[wid * 2 + 1] = qs; }
    __syncthreads();
    if (tid == 0) {
      double e = lred[0] + lred[2] + lred[4] + lred[6];
      double qq = lred[1] + lred[3] + lred[5] + lred[7];
      bpart[(size_t)blockIdx.x * 2] = e;
      bpart[(size_t)blockIdx.x * 2 + 1] = qq;
    }
  }
}

// ---------------------------------------------------------------------------
// Kernel 2c: vq_hist — per-block LDS histograms over 512 rows each, plain
// coalesced partial stores (exact integer partials; zero global atomics).
// ---------------------------------------------------------------------------
__global__ __launch_bounds__(256) void vq_hist(
    const unsigned int* __restrict__ bidx_g, unsigned int* __restrict__ hist_part) {
  __shared__ unsigned int hist[K_CODES];
  const int tid = threadIdx.x;
#pragma unroll
  for (int i = 0; i < K_CODES / 256; ++i) hist[i * 256 + tid] = 0;
  __syncthreads();
  const int base = blockIdx.x * 512;
#pragma unroll
  for (int i = 0; i < 2; ++i) {
    unsigned int b = bidx_g[base + i * 256 + tid];
    atomicAdd(&hist[b], 1u);
  }
  __syncthreads();
  unsigned int* dst = hist_part + (size_t)blockIdx.x * K_CODES;
#pragma unroll
  for (int i = 0; i < K_CODES / 256; ++i) dst[i * 256 + tid] = hist[i * 256 + tid];
}

// ---------------------------------------------------------------------------
// Kernel 2d: vq_hsum — parallel partial-sum (16 blocks x 256 threads;
// thread k sums hist_part[b][k] over b, coalesced across k).  Exact integer
// sum, order-independent.
// ---------------------------------------------------------------------------
__global__ __launch_bounds__(256) void vq_hsum(
    const unsigned int* __restrict__ hist_part, unsigned int* __restrict__ counts) {
  const int k = blockIdx.x * 256 + threadIdx.x;
  unsigned int c = 0;
#pragma unroll 8
  for (int b = 0; b < 64; ++b) c += hist_part[(size_t)b * K_CODES + k];
  counts[k] = c;
}

// ---------------------------------------------------------------------------
// Kernel 3: finalize scalars (r8-validated form: counts read directly).
// ---------------------------------------------------------------------------
__global__ __launch_bounds__(256) void vq_final(
    const unsigned int* __restrict__ counts, const double* __restrict__ bpart,
    float* __restrict__ out_scalars) {
  double s = 0.0;
  for (int k = threadIdx.x; k < K_CODES; k += 256) {
    float p = (float)counts[k] * (1.0f / 32768.0f);
    float term = p * logf(p + 1e-10f);
    s += (double)term;
  }
  double e = 0.0, qq = 0.0;
  for (int b = threadIdx.x; b < 1024; b += 256) {
    e += bpart[2 * b];
    qq += bpart[2 * b + 1];
  }
#pragma unroll
  for (int off = 32; off >= 1; off >>= 1) {
    s += __shfl_down(s, off, 64);
    e += __shfl_down(e, off, 64);
    qq += __shfl_down(qq, off, 64);
  }
  __shared__ double red[12];
  if ((threadIdx.x & 63) == 0) {
    int w = threadIdx.x >> 6;
    red[w] = s; red[4 + w] = e; red[8 + w] = qq;
  }
  __syncthreads();
  if (threadIdx.x == 0) {
    double tot = red[0] + red[1] + red[2] + red[3];
    double et = red[4] + red[5] + red[6] + red[7];
    double qt = red[8] + red[9] + red[10] + red[11];
    float e_lat = (float)(et / (double)(B_ROWS * D_DIM));
    float q_lat = (float)(qt / (double)(B_ROWS * D_DIM));
    float vq = q_lat + 0.25f * e_lat;   // fl(q + fl(0.25*e)); 0.25*e exact
    out_scalars[0] = vq;
    out_scalars[1] = e_lat;
    out_scalars[2] = q_lat;
    out_scalars[3] = expf(-(float)tot);
  }
}

extern "C" void kernel_launch(void* const* d_in, const int* in_sizes, int n_in,
                              void* d_out, int out_size, void* d_ws, size_t ws_size,
                              hipStream_t stream) {
  const float* x = (const float*)d_in[0];
  const float* emb = (const float*)d_in[1];
  float* out = (float*)d_out;

  // ws layout (~6.1 MB):
  //   bpart  f64[2048]        @0        (16384B)
  //   x2     f32[32768]       @16400
  //   e2     f32[4096]        @147472
  //   eb     u16[4096*128]    @163856   (1MB, ends 1212432)
  //   lists_g u16[32768*64]   @1212432  (4MB, ends 5406736);
  //          hist_part u32[64*4096] (1MB) overlays @1212432 after tail2
  //   cnt_g  u32[32768]       @5406736  (ends 5537808, memset-zeroed);
  //          counts u32[4096] overlays @5406736 after tail2 consumed cnt_g
  //   bidx_g u32[32768]       @5537808  (ends 5668880)
  //   pmin   f32[65536]       @5668880  (ends 5931024)
  //   mlims  f32[32768]       @5931024  (ends 6062096)
  double* bpart = (double*)d_ws;
  float* x2 = (float*)((char*)d_ws + 16400);
  float* e2 = (float*)((char*)d_ws + 147472);
  unsigned short* eb = (unsigned short*)((char*)d_ws + 163856);
  unsigned short* lists_g = (unsigned short*)((char*)d_ws + 1212432);
  unsigned int* hist_part = (unsigned int*)((char*)d_ws + 1212432);
  unsigned int* cnt_g = (unsigned int*)((char*)d_ws + 5406736);
  unsigned int* counts = (unsigned int*)((char*)d_ws + 5406736);
  unsigned int* bidx_g = (unsigned int*)((char*)d_ws + 5537808);
  float* pmin = (float*)((char*)d_ws + 5668880);
  float* mlims = (float*)((char*)d_ws + 5931024);

  float* out_idx = out + (size_t)B_ROWS * D_DIM;
  float* out_scalars = out_idx + B_ROWS;

  hipMemsetAsync(cnt_g, 0, 32768 * 4, stream);  // zero slot counters
  prep<<<512, 256, 0, stream>>>(x, emb, x2, e2, eb);
  vq_scanA<<<1024, 256, 0, stream>>>(x, eb, e2, pmin);
  vq_merge<<<128, 256, 0, stream>>>(pmin, mlims);
  vq_scanB<<<1024, 256, 0, stream>>>(x, eb, e2, mlims, lists_g, cnt_g);
  vq_tail2<<<B_ROWS / 32, 256, 0, stream>>>(x, emb, x2, e2, lists_g, cnt_g,
                                            out, out_idx, bidx_g, bpart);
  vq_hist<<<64, 256, 0, stream>>>(bidx_g, hist_part);
  vq_hsum<<<K_CODES / 256, 256, 0, stream>>>(hist_part, counts);
  vq_final<<<1, 256, 0, stream>>>(counts, bpart, out_scalars);
}

// Round 15
// 208.169 us; speedup vs baseline: 1.4061x; 1.4061x over previous
//
#include <hip/hip_runtime.h>
#include <math.h>

#define B_ROWS 32768
#define K_CODES 4096
#define D_DIM 128
#define MARGIN 1.5e-3f
#define CAP 64

typedef short bf16x8 __attribute__((ext_vector_type(8)));
typedef float f32x4 __attribute__((ext_vector_type(4)));

// RNE float->bf16 (finite inputs only)
__device__ __forceinline__ unsigned short f2bf(float f) {
  union { float f; unsigned int u; } v; v.f = f;
  unsigned int r = (v.u + 0x7FFFu + ((v.u >> 16) & 1u)) >> 16;
  return (unsigned short)r;
}

// async 16B global->LDS (wave-uniform LDS base + lane*16; per-lane global src)
__device__ __forceinline__ void gll16(const void* g, void* l) {
  __builtin_amdgcn_global_load_lds(
      (const __attribute__((address_space(1))) unsigned int*)g,
      (__attribute__((address_space(3))) unsigned int*)l, 16, 0, 0);
}

// ---------------------------------------------------------------------------
// Kernel 1: prep — x2/e2 (numpy pairwise order, validated) + eb bf16 cast in
// MFMA-FRAGMENT order (validated r4): og = tile*256 + ks*64 + q*16 + lr maps
// to emb row tile*16+lr, cols ks*32+q*8 .. +7.  Per chunk (8 tiles) eb is a
// CONTIGUOUS 32KB span — enables linear LDS staging in vq_scan.
// ---------------------------------------------------------------------------
__global__ __launch_bounds__(256) void prep(const float* __restrict__ x,
                                            const float* __restrict__ emb,
                                            float* __restrict__ x2,
                                            float* __restrict__ e2,
                                            unsigned short* __restrict__ ebb) {
  const int t0 = blockIdx.x * 256 + threadIdx.x;
  const int stride = gridDim.x * 256;
  for (int s = t0; s < B_ROWS * 8; s += stride) {
    int row = s >> 3, lane = s & 7;
    const float* src = x + (size_t)row * D_DIM;
    float v = src[lane];
    float t = v * v;
    asm volatile("" : "+v"(t));
    float acc = t;
#pragma unroll
    for (int i = 1; i < 16; ++i) {
      float w = src[i * 8 + lane];
      float tt = w * w;
      asm volatile("" : "+v"(tt));
      acc = acc + tt;
    }
    acc = acc + __shfl_xor(acc, 1, 64);
    acc = acc + __shfl_xor(acc, 2, 64);
    acc = acc + __shfl_xor(acc, 4, 64);
    if (lane == 0) x2[row] = acc;
  }
  for (int s = t0; s < K_CODES * 8; s += stride) {
    int row = s >> 3, lane = s & 7;
    const float* src = emb + (size_t)row * D_DIM;
    float v = src[lane];
    float t = v * v;
    asm volatile("" : "+v"(t));
    float acc = t;
#pragma unroll
    for (int i = 1; i < 16; ++i) {
      float w = src[i * 8 + lane];
      float tt = w * w;
      asm volatile("" : "+v"(tt));
      acc = acc + tt;
    }
    acc = acc + __shfl_xor(acc, 1, 64);
    acc = acc + __shfl_xor(acc, 2, 64);
    acc = acc + __shfl_xor(acc, 4, 64);
    if (lane == 0) e2[row] = acc;
  }
  for (int og = t0; og < K_CODES * D_DIM / 8; og += stride) {
    int tile = og >> 8, ks = (og >> 6) & 3, qq = (og >> 4) & 3, lr2 = og & 15;
    const float* src = emb + (size_t)(tile * 16 + lr2) * D_DIM + ks * 32 + qq * 8;
    float4 a = *(const float4*)src;
    float4 b = *(const float4*)(src + 4);
    ushort4 o0 = make_ushort4(f2bf(a.x), f2bf(a.y), f2bf(a.z), f2bf(a.w));
    ushort4 o1 = make_ushort4(f2bf(b.x), f2bf(b.y), f2bf(b.z), f2bf(b.w));
    ((ushort4*)ebb)[og * 2] = o0;
    ((ushort4*)ebb)[og * 2 + 1] = o1;
  }
}

// ---------------------------------------------------------------------------
// Kernel 2a: vq_scan — r12 structure (64 rows/block, 256 thr, 512 blocks,
// two passes, LDS-atomic collect) + ASYNC WAVE-PRIVATE eb STAGING:
// each wave double-buffers its own 2 tiles (8KB) per chunk via
// global_load_lds(16B) with counted s_waitcnt vmcnt(10) — 8 tile-loads + 2
// e2 prefetch loads per chunk stay in flight across the compute block.
// Wave-private buffers -> NO barriers in the loop, no cross-wave races.
// Staged bytes and fmin/MFMA sequence bit-identical to r12.
// ---------------------------------------------------------------------------
__global__ __launch_bounds__(256, 2) void vq_scan(
    const float* __restrict__ x, const unsigned short* __restrict__ eb,
    const float* __restrict__ e2g,
    unsigned short* __restrict__ lists_g, unsigned int* __restrict__ cnt_g) {
  __shared__ bf16x8 ebuf[2][2048];        // 64KB: [buf][wid*512 + t*64 + lane]
  __shared__ unsigned short lists[64 * CAP];  // 8KB
  __shared__ float m2[256];
  __shared__ float mlims[64];
  __shared__ unsigned int cnt[64];

  const int tid = threadIdx.x;
  const int wid = tid >> 6;
  const int lane = tid & 63;
  const int q = lane >> 4, lr = lane & 15;
  const int rowbase = blockIdx.x * 64;
  const char* ebB = (const char*)eb;

  // hoist A fragments (r12 verbatim)
  bf16x8 af[4][4];
#pragma unroll
  for (int mi = 0; mi < 4; ++mi) {
    const float* xr = x + (size_t)(rowbase + mi * 16 + lr) * D_DIM;
#pragma unroll
    for (int ks = 0; ks < 4; ++ks) {
      float4 v0 = *(const float4*)(xr + ks * 32 + q * 8);
      float4 v1 = *(const float4*)(xr + ks * 32 + q * 8 + 4);
      bf16x8 f;
      f[0] = (short)f2bf(v0.x); f[1] = (short)f2bf(v0.y);
      f[2] = (short)f2bf(v0.z); f[3] = (short)f2bf(v0.w);
      f[4] = (short)f2bf(v1.x); f[5] = (short)f2bf(v1.y);
      f[6] = (short)f2bf(v1.z); f[7] = (short)f2bf(v1.w);
      af[mi][ks] = f;
    }
  }
  if (tid < 64) cnt[tid] = 0;   // ready before pass B (barrier below)

  // ---------------- pass A: global min of t~ per row ----------------
  float rm[4][4];
#pragma unroll
  for (int mi = 0; mi < 4; ++mi)
#pragma unroll
    for (int rg = 0; rg < 4; ++rg) rm[mi][rg] = 3.4e38f;

  {
    // prologue: stage chunk 0 + e2(0)
    {
      const char* src = ebB + wid * 8192 + lane * 16;
      bf16x8* dst = &ebuf[0][wid * 512];
#pragma unroll
      for (int t = 0; t < 8; ++t) gll16(src + t * 1024, (void*)(dst + t * 64));
    }
    float evA0 = e2g[(wid * 2) * 16 + lr];
    float evA1 = e2g[(wid * 2 + 1) * 16 + lr];

#pragma unroll 1
    for (int ch = 0; ch < 32; ++ch) {
      float evN0 = 0.f, evN1 = 0.f;
      if (ch < 31) {
        const char* src = ebB + (size_t)(ch + 1) * 32768 + wid * 8192 + lane * 16;
        bf16x8* dst = &ebuf[(ch + 1) & 1][wid * 512];
#pragma unroll
        for (int t = 0; t < 8; ++t) gll16(src + t * 1024, (void*)(dst + t * 64));
        evN0 = e2g[(ch + 1) * 128 + (wid * 2) * 16 + lr];
        evN1 = e2g[(ch + 1) * 128 + (wid * 2 + 1) * 16 + lr];
        asm volatile("s_waitcnt vmcnt(10)" ::: "memory");
      } else {
        asm volatile("s_waitcnt vmcnt(0)" ::: "memory");
      }
      const bf16x8* wb = &ebuf[ch & 1][wid * 512];
      bf16x8 bf[2][4];
#pragma unroll
      for (int ni = 0; ni < 2; ++ni)
#pragma unroll
        for (int ks = 0; ks < 4; ++ks) bf[ni][ks] = wb[ni * 256 + ks * 64 + lane];
      f32x4 acc[4][2];
#pragma unroll
      for (int mi = 0; mi < 4; ++mi)
#pragma unroll
        for (int ni = 0; ni < 2; ++ni) {
          f32x4 z = {0.f, 0.f, 0.f, 0.f};
          acc[mi][ni] = z;
        }
#pragma unroll
      for (int ks = 0; ks < 4; ++ks)
#pragma unroll
        for (int mi = 0; mi < 4; ++mi)
#pragma unroll
          for (int ni = 0; ni < 2; ++ni)
            acc[mi][ni] = __builtin_amdgcn_mfma_f32_16x16x32_bf16(
                af[mi][ks], bf[ni][ks], acc[mi][ni], 0, 0, 0);
#pragma unroll
      for (int ni = 0; ni < 2; ++ni) {
        float ev = (ni == 0) ? evA0 : evA1;
#pragma unroll
        for (int mi = 0; mi < 4; ++mi)
#pragma unroll
          for (int rg = 0; rg < 4; ++rg) {
            float t = __builtin_fmaf(-2.0f, acc[mi][ni][rg], ev);
            rm[mi][rg] = fminf(rm[mi][rg], t);
          }
      }
      evA0 = evN0; evA1 = evN1;
    }
  }

  // reduce min across the 16 col-lanes, then across the 4 waves (r12 verbatim)
#pragma unroll
  for (int mi = 0; mi < 4; ++mi)
#pragma unroll
    for (int rg = 0; rg < 4; ++rg) {
      float v = rm[mi][rg];
      v = fminf(v, __shfl_xor(v, 1, 64));
      v = fminf(v, __shfl_xor(v, 2, 64));
      v = fminf(v, __shfl_xor(v, 4, 64));
      v = fminf(v, __shfl_xor(v, 8, 64));
      if (lr == 0) m2[(mi * 16 + q * 4 + rg) * 4 + wid] = v;
    }
  __syncthreads();
  if (tid < 64) {
    float a = fminf(m2[tid * 4], m2[tid * 4 + 1]);
    float b = fminf(m2[tid * 4 + 2], m2[tid * 4 + 3]);
    mlims[tid] = fminf(a, b) + MARGIN;
  }
  __syncthreads();

  // ---------------- pass B: collect candidates (LDS-atomic, r12) ----------
  float ml[4][4];
#pragma unroll
  for (int mi = 0; mi < 4; ++mi)
#pragma unroll
    for (int rg = 0; rg < 4; ++rg) ml[mi][rg] = mlims[mi * 16 + q * 4 + rg];

  {
    {
      const char* src = ebB + wid * 8192 + lane * 16;
      bf16x8* dst = &ebuf[0][wid * 512];
#pragma unroll
      for (int t = 0; t < 8; ++t) gll16(src + t * 1024, (void*)(dst + t * 64));
    }
    float evA0 = e2g[(wid * 2) * 16 + lr];
    float evA1 = e2g[(wid * 2 + 1) * 16 + lr];

#pragma unroll 1
    for (int ch = 0; ch < 32; ++ch) {
      float evN0 = 0.f, evN1 = 0.f;
      if (ch < 31) {
        const char* src = ebB + (size_t)(ch + 1) * 32768 + wid * 8192 + lane * 16;
        bf16x8* dst = &ebuf[(ch + 1) & 1][wid * 512];
#pragma unroll
        for (int t = 0; t < 8; ++t) gll16(src + t * 1024, (void*)(dst + t * 64));
        evN0 = e2g[(ch + 1) * 128 + (wid * 2) * 16 + lr];
        evN1 = e2g[(ch + 1) * 128 + (wid * 2 + 1) * 16 + lr];
        asm volatile("s_waitcnt vmcnt(10)" ::: "memory");
      } else {
        asm volatile("s_waitcnt vmcnt(0)" ::: "memory");
      }
      const bf16x8* wb = &ebuf[ch & 1][wid * 512];
      bf16x8 bf[2][4];
#pragma unroll
      for (int ni = 0; ni < 2; ++ni)
#pragma unroll
        for (int ks = 0; ks < 4; ++ks) bf[ni][ks] = wb[ni * 256 + ks * 64 + lane];
      f32x4 acc[4][2];
#pragma unroll
      for (int mi = 0; mi < 4; ++mi)
#pragma unroll
        for (int ni = 0; ni < 2; ++ni) {
          f32x4 z = {0.f, 0.f, 0.f, 0.f};
          acc[mi][ni] = z;
        }
#pragma unroll
      for (int ks = 0; ks < 4; ++ks)
#pragma unroll
        for (int mi = 0; mi < 4; ++mi)
#pragma unroll
          for (int ni = 0; ni < 2; ++ni)
            acc[mi][ni] = __builtin_amdgcn_mfma_f32_16x16x32_bf16(
                af[mi][ks], bf[ni][ks], acc[mi][ni], 0, 0, 0);
#pragma unroll
      for (int ni = 0; ni < 2; ++ni) {
        int colbase = ch * 128 + (wid * 2 + ni) * 16 + lr;
        float ev = (ni == 0) ? evA0 : evA1;
#pragma unroll
        for (int mi = 0; mi < 4; ++mi)
#pragma unroll
          for (int rg = 0; rg < 4; ++rg) {
            float t = __builtin_fmaf(-2.0f, acc[mi][ni][rg], ev);
            if (t <= ml[mi][rg]) {
              int row = mi * 16 + q * 4 + rg;
              unsigned int p = atomicAdd(&cnt[row], 1u);
              if (p < CAP) lists[row * CAP + p] = (unsigned short)colbase;
            }
          }
      }
      evA0 = evN0; evA1 = evN1;
    }
  }

  // ---------------- write lists/cnt to workspace (r12 verbatim) ----------
  __syncthreads();
  // 64*CAP = 4096 u16 = 8192B = 1024 ushort4 (8B each) -> 4 stores/thread
#pragma unroll
  for (int p = 0; p < 4; ++p)
    ((ushort4*)(lists_g + (size_t)rowbase * CAP))[p * 256 + tid] =
        ((const ushort4*)lists)[p * 256 + tid];
  if (tid < 64) cnt_g[rowbase + tid] = cnt[tid];
}

// ---------------------------------------------------------------------------
// Kernel 2b: vq_tail2 — rescore + gather/losses (r12 verbatim: no global
// atomics, CAP=64, parallel fallback reduction).  32 rows/block.
// ---------------------------------------------------------------------------
__global__ __launch_bounds__(256) void vq_tail2(
    const float* __restrict__ x, const float* __restrict__ emb,
    const float* __restrict__ x2g, const float* __restrict__ e2g,
    const unsigned short* __restrict__ lists_g,
    const unsigned int* __restrict__ cnt_g,
    float* __restrict__ out_q, float* __restrict__ out_idx,
    unsigned int* __restrict__ bidx_g, double* __restrict__ bpart) {
  __shared__ float xf[32 * 132];       // 16896B
  __shared__ float redv[256];
  __shared__ int redi[256];
  __shared__ unsigned int cnts[32];
  __shared__ int bidxs[32];
  __shared__ double lred[8];
  __shared__ int ovflag;

  const int tid = threadIdx.x;
  const int wid = tid >> 6;
  const int lane = tid & 63;
  const int rowbase = blockIdx.x * 32;

  if (tid < 32) cnts[tid] = cnt_g[rowbase + tid];
  // stage fp32 x rows (coalesced)
  {
    const float4* src = (const float4*)(x + (size_t)rowbase * D_DIM);
#pragma unroll
    for (int p = 0; p < 4; ++p) {
      int idx = p * 256 + tid;            // float4 index over 32x128
      int r = idx >> 5, c = idx & 31;
      *(float4*)(xf + r * 132 + c * 4) = src[idx];
    }
  }
  __syncthreads();

  // 8 lanes per row; per-candidate fp32 chain identical to validated version.
  {
    int gr = tid >> 3, sub = tid & 7;
    int c = (int)cnts[gr];
    if (c <= CAP) {
      float xs2 = x2g[rowbase + gr];
      const float* xr = xf + gr * 132;
      float best = 3.4e38f;
      int bidx = 0x7fffffff;
      const unsigned short* lrow = lists_g + (size_t)(rowbase + gr) * CAP;
      for (int j = sub; j < c; j += 8) {
        int col = lrow[j];
        float dot = 0.f;
        const float4* ev = (const float4*)(emb + (size_t)col * D_DIM);
#pragma unroll 8
        for (int d4 = 0; d4 < 32; ++d4) {  // exact ascending-d fmaf chain
          float4 e4 = ev[d4];
          dot = __builtin_fmaf(xr[d4 * 4 + 0], e4.x, dot);
          dot = __builtin_fmaf(xr[d4 * 4 + 1], e4.y, dot);
          dot = __builtin_fmaf(xr[d4 * 4 + 2], e4.z, dot);
          dot = __builtin_fmaf(xr[d4 * 4 + 3], e4.w, dot);
        }
        float t1 = xs2 + e2g[col];                 // fl(x2+e2)
        float s = __builtin_fmaf(-2.0f, dot, t1);  // fl(t1 - 2*dot)
        if (s < best || (s == best && col < bidx)) { best = s; bidx = col; }
      }
#pragma unroll
      for (int off = 1; off <= 4; off <<= 1) {
        float ov = __shfl_xor(best, off, 64);
        int oi = __shfl_xor(bidx, off, 64);
        if (ov < best || (ov == best && oi < bidx)) { best = ov; bidx = oi; }
      }
      if (sub == 0) {
        out_idx[rowbase + gr] = (float)bidx;
        bidxs[gr] = bidx;
        bidx_g[rowbase + gr] = (unsigned int)bidx;
      }
    }
  }

  // overflow flag (block-uniform; with CAP=64 expected never taken)
  if (tid == 0) {
    int f = 0;
    for (int r = 0; r < 32; ++r) f |= (cnts[r] > CAP) ? 1 : 0;
    ovflag = f;
  }
  __syncthreads();

  if (ovflag) {
    for (int r = 0; r < 32; ++r) {
      if (cnts[r] <= CAP) continue;
      float xs2 = x2g[rowbase + r];
      const float* xr = xf + r * 132;
      float lbest = 3.4e38f;
      int lidx = 0x7fffffff;
      for (int c0 = tid; c0 < K_CODES; c0 += 256) {
        float dot = 0.f;
        const float4* ev = (const float4*)(emb + (size_t)c0 * D_DIM);
        for (int d4 = 0; d4 < 32; ++d4) {
          float4 e4 = ev[d4];
          dot = __builtin_fmaf(xr[d4 * 4 + 0], e4.x, dot);
          dot = __builtin_fmaf(xr[d4 * 4 + 1], e4.y, dot);
          dot = __builtin_fmaf(xr[d4 * 4 + 2], e4.z, dot);
          dot = __builtin_fmaf(xr[d4 * 4 + 3], e4.w, dot);
        }
        float s = __builtin_fmaf(-2.0f, dot, xs2 + e2g[c0]);
        if (s < lbest || (s == lbest && c0 < lidx)) { lbest = s; lidx = c0; }
      }
      redv[tid] = lbest;
      redi[tid] = lidx;
      __syncthreads();
      // parallel lexicographic reduce: 256 -> 128 -> 64 -> wave shuffle
      if (tid < 128) {
        float v2 = redv[tid + 128]; int i2 = redi[tid + 128];
        if (v2 < redv[tid] || (v2 == redv[tid] && i2 < redi[tid])) {
          redv[tid] = v2; redi[tid] = i2;
        }
      }
      __syncthreads();
      if (tid < 64) {
        float bv = redv[tid]; int bi = redi[tid];
        float v2 = redv[tid + 64]; int i2 = redi[tid + 64];
        if (v2 < bv || (v2 == bv && i2 < bi)) { bv = v2; bi = i2; }
#pragma unroll
        for (int off = 32; off >= 1; off >>= 1) {
          float ov = __shfl_down(bv, off, 64);
          int oi = __shfl_down(bi, off, 64);
          if (ov < bv || (ov == bv && oi < bi)) { bv = ov; bi = oi; }
        }
        if (tid == 0) {
          out_idx[rowbase + r] = (float)bi;
          bidxs[r] = bi;
          bidx_g[rowbase + r] = (unsigned int)bi;
        }
      }
      __syncthreads();
    }
  }
  __syncthreads();  // bidxs ready for all rows

  // ---------------- fused gather + straight-through + losses ----------------
  {
    int gr = tid >> 3, seg = tid & 7;   // 8 threads/row, 16 floats each
    int gidx = bidxs[gr];
    const float4* ev = (const float4*)(emb + (size_t)gidx * D_DIM + seg * 16);
    const float* xvp = xf + gr * 132 + seg * 16;
    float4* oq = (float4*)(out_q + (size_t)(rowbase + gr) * D_DIM + seg * 16);
    double es = 0.0, qs = 0.0;
#pragma unroll
    for (int j = 0; j < 4; ++j) {
      float4 e4 = ev[j];
      float4 xv = *(const float4*)(xvp + j * 4);
      float d0 = e4.x - xv.x, d1 = e4.y - xv.y, d2 = e4.z - xv.z, d3 = e4.w - xv.w;
      float s0 = xv.x + d0, s1 = xv.y + d1, s2 = xv.z + d2, s3 = xv.w + d3;
      oq[j] = make_float4(s0, s1, s2, s3);
      float g0 = s0 - xv.x, g1 = s1 - xv.y, g2 = s2 - xv.z, g3 = s3 - xv.w;
      es += (double)(d0 * d0) + (double)(d1 * d1) + (double)(d2 * d2) + (double)(d3 * d3);
      qs += (double)(g0 * g0) + (double)(g1 * g1) + (double)(g2 * g2) + (double)(g3 * g3);
    }
#pragma unroll
    for (int off = 32; off >= 1; off >>= 1) {
      es += __shfl_down(es, off, 64);
      qs += __shfl_down(qs, off, 64);
    }
    if (lane == 0) { lred[wid * 2] = es; lred[wid * 2 + 1] = qs; }
    __syncthreads();
    if (tid == 0) {
      double e = lred[0] + lred[2] + lred[4] + lred[6];
      double qq = lred[1] + lred[3] + lred[5] + lred[7];
      bpart[(size_t)blockIdx.x * 2] = e;
      bpart[(size_t)blockIdx.x * 2 + 1] = qq;
    }
  }
}

// ---------------------------------------------------------------------------
// Kernel 2c: vq_hist — per-block LDS histograms over 512 rows each, plain
// coalesced partial stores (exact integer partials; zero global atomics).
// ---------------------------------------------------------------------------
__global__ __launch_bounds__(256) void vq_hist(
    const unsigned int* __restrict__ bidx_g, unsigned int* __restrict__ hist_part) {
  __shared__ unsigned int hist[K_CODES];
  const int tid = threadIdx.x;
#pragma unroll
  for (int i = 0; i < K_CODES / 256; ++i) hist[i * 256 + tid] = 0;
  __syncthreads();
  const int base = blockIdx.x * 512;
#pragma unroll
  for (int i = 0; i < 2; ++i) {
    unsigned int b = bidx_g[base + i * 256 + tid];
    atomicAdd(&hist[b], 1u);
  }
  __syncthreads();
  unsigned int* dst = hist_part + (size_t)blockIdx.x * K_CODES;
#pragma unroll
  for (int i = 0; i < K_CODES / 256; ++i) dst[i * 256 + tid] = hist[i * 256 + tid];
}

// ---------------------------------------------------------------------------
// Kernel 2d: vq_hsum — parallel partial-sum (16 blocks x 256 threads;
// thread k sums hist_part[b][k] over b, coalesced across k).  Exact integer
// sum, order-independent.
// ---------------------------------------------------------------------------
__global__ __launch_bounds__(256) void vq_hsum(
    const unsigned int* __restrict__ hist_part, unsigned int* __restrict__ counts) {
  const int k = blockIdx.x * 256 + threadIdx.x;
  unsigned int c = 0;
#pragma unroll 8
  for (int b = 0; b < 64; ++b) c += hist_part[(size_t)b * K_CODES + k];
  counts[k] = c;
}

// ---------------------------------------------------------------------------
// Kernel 3: finalize scalars (r8-validated form: counts read directly).
// ---------------------------------------------------------------------------
__global__ __launch_bounds__(256) void vq_final(
    const unsigned int* __restrict__ counts, const double* __restrict__ bpart,
    float* __restrict__ out_scalars) {
  double s = 0.0;
  for (int k = threadIdx.x; k < K_CODES; k += 256) {
    float p = (float)counts[k] * (1.0f / 32768.0f);
    float term = p * logf(p + 1e-10f);
    s += (double)term;
  }
  double e = 0.0, qq = 0.0;
  for (int b = threadIdx.x; b < 1024; b += 256) {
    e += bpart[2 * b];
    qq += bpart[2 * b + 1];
  }
#pragma unroll
  for (int off = 32; off >= 1; off >>= 1) {
    s += __shfl_down(s, off, 64);
    e += __shfl_down(e, off, 64);
    qq += __shfl_down(qq, off, 64);
  }
  __shared__ double red[12];
  if ((threadIdx.x & 63) == 0) {
    int w = threadIdx.x >> 6;
    red[w] = s; red[4 + w] = e; red[8 + w] = qq;
  }
  __syncthreads();
  if (threadIdx.x == 0) {
    double tot = red[0] + red[1] + red[2] + red[3];
    double et = red[4] + red[5] + red[6] + red[7];
    double qt = red[8] + red[9] + red[10] + red[11];
    float e_lat = (float)(et / (double)(B_ROWS * D_DIM));
    float q_lat = (float)(qt / (double)(B_ROWS * D_DIM));
    float vq = q_lat + 0.25f * e_lat;   // fl(q + fl(0.25*e)); 0.25*e exact
    out_scalars[0] = vq;
    out_scalars[1] = e_lat;
    out_scalars[2] = q_lat;
    out_scalars[3] = expf(-(float)tot);
  }
}

extern "C" void kernel_launch(void* const* d_in, const int* in_sizes, int n_in,
                              void* d_out, int out_size, void* d_ws, size_t ws_size,
                              hipStream_t stream) {
  const float* x = (const float*)d_in[0];
  const float* emb = (const float*)d_in[1];
  float* out = (float*)d_out;

  // ws layout (5.67 MB, all regions fully overwritten before read — no memset):
  //   bpart  f64[2048]        @0        (16384B)
  //   x2     f32[32768]       @16400
  //   e2     f32[4096]        @147472
  //   eb     u16[4096*128]    @163856   (1MB, ends 1212432)
  //   lists_g u16[32768*CAP=64] @1212432 (4MB, ends 5406736);
  //          hist_part u32[64*4096] (1MB) overlays @1212432 after tail2
  //   cnt_g  u32[32768]       @5406736  (ends 5537808); counts u32[4096]
  //          overlays @5406736 after tail2 consumed cnt_g
  //   bidx_g u32[32768]       @5537808  (ends 5668880)
  double* bpart = (double*)d_ws;
  float* x2 = (float*)((char*)d_ws + 16400);
  float* e2 = (float*)((char*)d_ws + 147472);
  unsigned short* eb = (unsigned short*)((char*)d_ws + 163856);
  unsigned short* lists_g = (unsigned short*)((char*)d_ws + 1212432);
  unsigned int* hist_part = (unsigned int*)((char*)d_ws + 1212432);
  unsigned int* cnt_g = (unsigned int*)((char*)d_ws + 5406736);
  unsigned int* counts = (unsigned int*)((char*)d_ws + 5406736);
  unsigned int* bidx_g = (unsigned int*)((char*)d_ws + 5537808);

  float* out_idx = out + (size_t)B_ROWS * D_DIM;
  float* out_scalars = out_idx + B_ROWS;

  prep<<<512, 256, 0, stream>>>(x, emb, x2, e2, eb);
  vq_scan<<<B_ROWS / 64, 256, 0, stream>>>(x, eb, e2, lists_g, cnt_g);
  vq_tail2<<<B_ROWS / 32, 256, 0, stream>>>(x, emb, x2, e2, lists_g, cnt_g,
                                            out, out_idx, bidx_g, bpart);
  vq_hist<<<64, 256, 0, stream>>>(bidx_g, hist_part);
  vq_hsum<<<K_CODES / 256, 256, 0, stream>>>(hist_part, counts);
  vq_final<<<1, 256, 0, stream>>>(counts, bpart, out_scalars);
}